// Round 1
// baseline (141.623 us; speedup 1.0000x reference)
//
#include <hip/hip_runtime.h>

// ---------------------------------------------------------------------------
// NNUE forward: gather+segment_sum -> [B,512] -> MLP 512->128->64->32->1
// Inputs (f32/i32): widx, bidx, wbatch(sorted), bbatch(sorted), stm,
//                   wemb[40960,256], bemb[40960,256], W1[512,128], b1,
//                   W2[128,64], b2, W3[64,32], b3, Wo[32,1], bo
// ---------------------------------------------------------------------------

__device__ __forceinline__ int lower_bound_i(const int* __restrict__ a, int n, int v) {
    int lo = 0, hi = n;
    while (lo < hi) {
        int mid = (lo + hi) >> 1;
        if (a[mid] < v) lo = mid + 1; else hi = mid;
    }
    return lo;
}

// grid (B, 2), block 64. side 0 = white, 1 = black.
// Each block sums its contiguous segment of embedding rows (batch is sorted)
// and writes its 256-float half of x[b] with the stm-conditional swap.
__global__ __launch_bounds__(64)
void nnue_accum(const int* __restrict__ widx, const int* __restrict__ bidx,
                const int* __restrict__ wbatch, const int* __restrict__ bbatch,
                const int* __restrict__ stm,
                const float* __restrict__ wemb, const float* __restrict__ bemb,
                float* __restrict__ x, int n_act)
{
    const int b    = blockIdx.x;
    const int side = blockIdx.y;
    const int*   __restrict__ idx   = side ? bidx   : widx;
    const int*   __restrict__ batch = side ? bbatch : wbatch;
    const float* __restrict__ emb   = side ? bemb   : wemb;

    const int start = lower_bound_i(batch, n_act, b);
    const int end   = lower_bound_i(batch, n_act, b + 1);

    const int c = (threadIdx.x << 2);  // float4 column
    float4 s0 = make_float4(0.f, 0.f, 0.f, 0.f);
    float4 s1 = s0, s2 = s0, s3 = s0;

    int r = start;
    for (; r + 4 <= end; r += 4) {
        const float4 v0 = *(const float4*)(emb + (size_t)idx[r + 0] * 256 + c);
        const float4 v1 = *(const float4*)(emb + (size_t)idx[r + 1] * 256 + c);
        const float4 v2 = *(const float4*)(emb + (size_t)idx[r + 2] * 256 + c);
        const float4 v3 = *(const float4*)(emb + (size_t)idx[r + 3] * 256 + c);
        s0.x += v0.x; s0.y += v0.y; s0.z += v0.z; s0.w += v0.w;
        s1.x += v1.x; s1.y += v1.y; s1.z += v1.z; s1.w += v1.w;
        s2.x += v2.x; s2.y += v2.y; s2.z += v2.z; s2.w += v2.w;
        s3.x += v3.x; s3.y += v3.y; s3.z += v3.z; s3.w += v3.w;
    }
    for (; r < end; ++r) {
        const float4 v0 = *(const float4*)(emb + (size_t)idx[r] * 256 + c);
        s0.x += v0.x; s0.y += v0.y; s0.z += v0.z; s0.w += v0.w;
    }
    s0.x += s1.x + s2.x + s3.x;
    s0.y += s1.y + s2.y + s3.y;
    s0.z += s1.z + s2.z + s3.z;
    s0.w += s1.w + s2.w + s3.w;

    // stm==0 -> concat([black, white]); else concat([white, black])
    const int off = (stm[b] == 0) ? (side ? 0 : 256) : (side ? 256 : 0);
    *(float4*)(x + (size_t)b * 512 + off + c) = s0;
}

// Layer 1: h1 = relu(x @ W1 + b1), x:[B,512], W1:[512,128].
// grid B/16, block 256 (4 waves). 16-row x tile in LDS (32 KB).
// Each wave: 4 rows; each lane owns output columns (2*lane, 2*lane+1).
__global__ __launch_bounds__(256)
void nnue_layer1(const float* __restrict__ x, const float* __restrict__ W1,
                 const float* __restrict__ b1, float* __restrict__ h1, int B)
{
    __shared__ float xs[16][512];
    const int tid  = threadIdx.x;
    const int row0 = blockIdx.x * 16;

    #pragma unroll
    for (int i = 0; i < 8; ++i) {
        const int e  = (i * 256 + tid) * 4;
        const int rr = e >> 9;
        const int cc = e & 511;
        if (row0 + rr < B)
            *(float4*)&xs[rr][cc] = *(const float4*)(x + (size_t)(row0 + rr) * 512 + cc);
    }
    __syncthreads();

    const int wave = tid >> 6;
    const int lane = tid & 63;
    const int j2   = lane * 2;     // output column pair
    const int wrow = wave * 4;     // first of this wave's 4 rows

    float2 acc[4];
    #pragma unroll
    for (int r2 = 0; r2 < 4; ++r2) { acc[r2].x = b1[j2]; acc[r2].y = b1[j2 + 1]; }

    for (int k = 0; k < 512; k += 4) {
        float4 xv[4];
        #pragma unroll
        for (int r2 = 0; r2 < 4; ++r2) xv[r2] = *(const float4*)&xs[wrow + r2][k];
        #pragma unroll
        for (int kk = 0; kk < 4; ++kk) {
            const float2 w = *(const float2*)(W1 + (size_t)(k + kk) * 128 + j2);
            #pragma unroll
            for (int r2 = 0; r2 < 4; ++r2) {
                const float xvv = (&xv[r2].x)[kk];
                acc[r2].x = fmaf(xvv, w.x, acc[r2].x);
                acc[r2].y = fmaf(xvv, w.y, acc[r2].y);
            }
        }
    }

    #pragma unroll
    for (int r2 = 0; r2 < 4; ++r2) {
        const int row = row0 + wrow + r2;
        if (row < B) {
            float2 o;
            o.x = fmaxf(acc[r2].x, 0.f);
            o.y = fmaxf(acc[r2].y, 0.f);
            *(float2*)(h1 + (size_t)row * 128 + j2) = o;
        }
    }
}

// Layers 2-4 fused: out = relu(relu(h1@W2+b2)@W3+b3)@Wo+bo.
// grid B/32, block 256 (4 waves), 8 rows per wave, weights staged in LDS.
__global__ __launch_bounds__(256)
void nnue_tail(const float* __restrict__ h1,
               const float* __restrict__ W2, const float* __restrict__ b2,
               const float* __restrict__ W3, const float* __restrict__ b3,
               const float* __restrict__ Wo, const float* __restrict__ bo,
               float* __restrict__ out, int B)
{
    __shared__ float W2s[128 * 64];
    __shared__ float W3s[64 * 32];
    __shared__ float Wos[32];
    __shared__ float h1row[4][128];
    __shared__ float h2row[4][64];

    const int tid = threadIdx.x;
    for (int i = tid; i < 128 * 64; i += 256) W2s[i] = W2[i];
    for (int i = tid; i < 64 * 32; i += 256)  W3s[i] = W3[i];
    if (tid < 32) Wos[tid] = Wo[tid];
    __syncthreads();

    const int wave = tid >> 6;
    const int lane = tid & 63;
    const float bias2 = b2[lane];
    const float bias3 = (lane < 32) ? b3[lane] : 0.f;
    const float wo    = (lane < 32) ? Wos[lane] : 0.f;
    const float bo0   = bo[0];

    #pragma unroll 1
    for (int it = 0; it < 8; ++it) {
        const int row = blockIdx.x * 32 + wave * 8 + it;
        if (row >= B) break;

        // stage this row's h1 (same-wave DS ordering, no barrier needed)
        h1row[wave][lane]      = h1[(size_t)row * 128 + lane];
        h1row[wave][lane + 64] = h1[(size_t)row * 128 + 64 + lane];

        float acc = bias2;
        #pragma unroll 8
        for (int k = 0; k < 128; ++k)
            acc = fmaf(h1row[wave][k], W2s[k * 64 + lane], acc);
        acc = fmaxf(acc, 0.f);
        h2row[wave][lane] = acc;

        float acc3 = 0.f;
        if (lane < 32) {
            acc3 = bias3;
            #pragma unroll 8
            for (int k = 0; k < 64; ++k)
                acc3 = fmaf(h2row[wave][k], W3s[k * 32 + lane], acc3);
            acc3 = fmaxf(acc3, 0.f) * wo;
        }
        // sum over lanes (lanes >= 32 contribute 0)
        #pragma unroll
        for (int s = 32; s >= 1; s >>= 1)
            acc3 += __shfl_xor(acc3, s, 64);
        if (lane == 0) out[row] = acc3 + bo0;
    }
}

extern "C" void kernel_launch(void* const* d_in, const int* in_sizes, int n_in,
                              void* d_out, int out_size, void* d_ws, size_t ws_size,
                              hipStream_t stream)
{
    const int*   widx   = (const int*)d_in[0];
    const int*   bidx   = (const int*)d_in[1];
    const int*   wbatch = (const int*)d_in[2];
    const int*   bbatch = (const int*)d_in[3];
    const int*   stm    = (const int*)d_in[4];
    const float* wemb   = (const float*)d_in[5];
    const float* bemb   = (const float*)d_in[6];
    const float* W1     = (const float*)d_in[7];
    const float* b1     = (const float*)d_in[8];
    const float* W2     = (const float*)d_in[9];
    const float* b2     = (const float*)d_in[10];
    const float* W3     = (const float*)d_in[11];
    const float* b3     = (const float*)d_in[12];
    const float* Wo     = (const float*)d_in[13];
    const float* bo     = (const float*)d_in[14];

    const int n_act = in_sizes[0];
    const int B     = in_sizes[4];

    float* x  = (float*)d_ws;                 // [B, 512]
    float* h1 = x + (size_t)B * 512;          // [B, 128]

    dim3 gA(B, 2);
    nnue_accum<<<gA, 64, 0, stream>>>(widx, bidx, wbatch, bbatch, stm,
                                      wemb, bemb, x, n_act);
    nnue_layer1<<<(B + 15) / 16, 256, 0, stream>>>(x, W1, b1, h1, B);
    nnue_tail<<<(B + 31) / 32, 256, 0, stream>>>(h1, W2, b2, W3, b3, Wo, bo,
                                                 (float*)d_out, B);
}

// Round 2
// 72.933 us; speedup vs baseline: 1.9418x; 1.9418x over previous
//
#include <hip/hip_runtime.h>
#include <hip/hip_bf16.h>

using bf16x8 = __attribute__((ext_vector_type(8))) short;
using f32x4  = __attribute__((ext_vector_type(4))) float;
using u16x8  = __attribute__((ext_vector_type(8))) unsigned short;

static __device__ __forceinline__ float bf2f(unsigned short u) {
    union { unsigned int i; float f; } v; v.i = ((unsigned int)u) << 16; return v.f;
}
static __device__ __forceinline__ unsigned short f2bf(float f) {
    __hip_bfloat16 h = __float2bfloat16(f);
    return *reinterpret_cast<unsigned short*>(&h);
}

__device__ __forceinline__ int lower_bound_i(const int* __restrict__ a, int n, int v) {
    int lo = 0, hi = n;
    while (lo < hi) {
        int mid = (lo + hi) >> 1;
        if (a[mid] < v) lo = mid + 1; else hi = mid;
    }
    return lo;
}

// ===========================================================================
// FAST PATH
// ===========================================================================

// Prep: convert tables f32->bf16, pack W1/W2 into MFMA B-fragment order,
// precompute segment bounds for both sides. Grid-stride over linear ranges.
__global__ __launch_bounds__(256)
void nnue_prep(const float* __restrict__ wemb, const float* __restrict__ bemb,
               const float* __restrict__ W1, const float* __restrict__ W2,
               const int* __restrict__ wbatch, const int* __restrict__ bbatch,
               unsigned short* __restrict__ wemb16, unsigned short* __restrict__ bemb16,
               unsigned short* __restrict__ W1p, unsigned short* __restrict__ W2p,
               int* __restrict__ segs, long long groups, int n_act, int B)
{
    const long long r0 = groups;            // wemb groups (8 elems each)
    const long long r1 = 2 * groups;        // bemb groups
    const long long r2 = r1 + 8192;         // W1p groups: 128 frags x 64 lanes
    const long long r3 = r2 + 1024;         // W2p groups: 16 frags x 64 lanes
    const long long r4 = r3 + 2LL * (B + 1);// seg bounds
    const long long stride = (long long)gridDim.x * blockDim.x;

    for (long long t = (long long)blockIdx.x * blockDim.x + threadIdx.x;
         t < r4; t += stride) {
        if (t < r1) {
            const int w = (t < r0);
            const long long g = w ? t : (t - r0);
            const float* src = (w ? wemb : bemb) + g * 8;
            unsigned short* dst = (w ? wemb16 : bemb16) + g * 8;
            const float4 a = *(const float4*)(src);
            const float4 b = *(const float4*)(src + 4);
            u16x8 o;
            o[0] = f2bf(a.x); o[1] = f2bf(a.y); o[2] = f2bf(a.z); o[3] = f2bf(a.w);
            o[4] = f2bf(b.x); o[5] = f2bf(b.y); o[6] = f2bf(b.z); o[7] = f2bf(b.w);
            *(u16x8*)dst = o;
        } else if (t < r2) {
            // W1p[(f*64+l)*8+i] = bf16(W1[kc*32+(l>>4)*8+i][nc*16+(l&15)]), f=kc*8+nc
            const int u = (int)(t - r1);
            const int f = u >> 6, l = u & 63;
            const int kc = f >> 3, nc = f & 7;
            const int krow = kc * 32 + (l >> 4) * 8;
            const int col  = nc * 16 + (l & 15);
            u16x8 o;
            #pragma unroll
            for (int i = 0; i < 8; ++i) o[i] = f2bf(W1[(size_t)(krow + i) * 128 + col]);
            *(u16x8*)(W1p + (size_t)u * 8) = o;
        } else if (t < r3) {
            const int u = (int)(t - r2);
            const int f = u >> 6, l = u & 63;
            const int kc = f >> 2, nc = f & 3;
            const int krow = kc * 32 + (l >> 4) * 8;
            const int col  = nc * 16 + (l & 15);
            u16x8 o;
            #pragma unroll
            for (int i = 0; i < 8; ++i) o[i] = f2bf(W2[(size_t)(krow + i) * 64 + col]);
            *(u16x8*)(W2p + (size_t)u * 8) = o;
        } else {
            const int u = (int)(t - r3);
            const int side = u / (B + 1);
            const int b = u - side * (B + 1);
            const int* bat = side ? bbatch : wbatch;
            segs[u] = lower_bound_i(bat, n_act, b);
        }
    }
}

// Accum: grid (B/4, 2), block 256 = 4 waves; wave w -> batch blockIdx.x*4+w.
// Reads bf16 rows (512B), lane covers 4 cols (8B), 8-deep unroll.
__global__ __launch_bounds__(256)
void nnue_accum16(const int* __restrict__ widx, const int* __restrict__ bidx,
                  const int* __restrict__ stm,
                  const unsigned short* __restrict__ wemb16,
                  const unsigned short* __restrict__ bemb16,
                  const int* __restrict__ segs,
                  unsigned short* __restrict__ x16, int B)
{
    const int wave = threadIdx.x >> 6, lane = threadIdx.x & 63;
    const int b    = blockIdx.x * 4 + wave;
    const int side = blockIdx.y;
    const int* __restrict__ idx = side ? bidx : widx;
    const unsigned short* __restrict__ emb = side ? bemb16 : wemb16;
    const int* __restrict__ sg = segs + side * (B + 1);

    const int rs = sg[b], re = sg[b + 1];
    const int col = lane * 4;
    float4 s = make_float4(0.f, 0.f, 0.f, 0.f);

    int r = rs;
    for (; r + 8 <= re; r += 8) {
        ushort4 v[8];
        #pragma unroll
        for (int u = 0; u < 8; ++u)
            v[u] = *(const ushort4*)(emb + (size_t)idx[r + u] * 256 + col);
        #pragma unroll
        for (int u = 0; u < 8; ++u) {
            s.x += bf2f(v[u].x); s.y += bf2f(v[u].y);
            s.z += bf2f(v[u].z); s.w += bf2f(v[u].w);
        }
    }
    for (; r + 4 <= re; r += 4) {
        ushort4 v[4];
        #pragma unroll
        for (int u = 0; u < 4; ++u)
            v[u] = *(const ushort4*)(emb + (size_t)idx[r + u] * 256 + col);
        #pragma unroll
        for (int u = 0; u < 4; ++u) {
            s.x += bf2f(v[u].x); s.y += bf2f(v[u].y);
            s.z += bf2f(v[u].z); s.w += bf2f(v[u].w);
        }
    }
    for (; r < re; ++r) {
        const ushort4 v = *(const ushort4*)(emb + (size_t)idx[r] * 256 + col);
        s.x += bf2f(v.x); s.y += bf2f(v.y); s.z += bf2f(v.z); s.w += bf2f(v.w);
    }

    const int off = (stm[b] == 0) ? (side ? 0 : 256) : (side ? 256 : 0);
    ushort4 o;
    o.x = f2bf(s.x); o.y = f2bf(s.y); o.z = f2bf(s.z); o.w = f2bf(s.w);
    *(ushort4*)(x16 + (size_t)b * 512 + off + col) = o;
}

// Fused MLP: layer1 (512->128) + layer2 (128->64) via bf16 MFMA,
// layer3 (64->32) + output dot on VALU. 32 rows/block, 4 waves.
__global__ __launch_bounds__(256)
void nnue_mlp16(const unsigned short* __restrict__ x16,
                const unsigned short* __restrict__ W1p, const float* __restrict__ b1,
                const unsigned short* __restrict__ W2p, const float* __restrict__ b2,
                const float* __restrict__ W3, const float* __restrict__ b3,
                const float* __restrict__ Wo, const float* __restrict__ bo,
                float* __restrict__ out, int B)
{
    __shared__ unsigned short h1s[32 * 128];  // bf16, XOR-swizzled 16B granules
    __shared__ float h2s[32][68];             // f32, padded
    __shared__ float W3s[64 * 32];

    const int tid = threadIdx.x, wave = tid >> 6, lane = tid & 63;
    const int row0 = blockIdx.x * 32;
    const int m = lane & 15, kg = lane >> 4;

    for (int i = tid; i < 64 * 32; i += 256) W3s[i] = W3[i];

    // ---- Layer 1: wave (wr, wc) computes rows [16wr,16wr+16) x cols [64wc,64wc+64)
    {
        const int wr = wave >> 1, wc = wave & 1;
        f32x4 acc[4] = {{0,0,0,0},{0,0,0,0},{0,0,0,0},{0,0,0,0}};
        const unsigned short* xrow = x16 + (size_t)(row0 + wr * 16 + m) * 512;
        #pragma unroll
        for (int kc = 0; kc < 16; ++kc) {
            const bf16x8 a = *(const bf16x8*)(xrow + kc * 32 + kg * 8);
            #pragma unroll
            for (int nc = 0; nc < 4; ++nc) {
                const bf16x8 bb = *(const bf16x8*)(W1p + (size_t)((kc * 8 + wc * 4 + nc) * 64 + lane) * 8);
                acc[nc] = __builtin_amdgcn_mfma_f32_16x16x32_bf16(a, bb, acc[nc], 0, 0, 0);
            }
        }
        #pragma unroll
        for (int nc = 0; nc < 4; ++nc) {
            const int col = wc * 64 + nc * 16 + m;
            const float bias = b1[col];
            #pragma unroll
            for (int reg = 0; reg < 4; ++reg) {
                const int row = wr * 16 + kg * 4 + reg;
                const float v = fmaxf(acc[nc][reg] + bias, 0.f);
                h1s[row * 128 + (((col >> 3) ^ (row & 15)) << 3) + (col & 7)] = f2bf(v);
            }
        }
    }
    __syncthreads();

    // ---- Layer 2: wave (mr, wc2): rows [16mr,+16) x cols [32wc2,+32), K=128
    {
        const int mr = wave >> 1, wc2 = wave & 1;
        f32x4 acc2[2] = {{0,0,0,0},{0,0,0,0}};
        const int row = mr * 16 + m;
        #pragma unroll
        for (int kc = 0; kc < 4; ++kc) {
            const int g = (kc * 4 + kg) ^ (row & 15);
            const bf16x8 a = *(const bf16x8*)&h1s[row * 128 + g * 8];
            #pragma unroll
            for (int ncl = 0; ncl < 2; ++ncl) {
                const bf16x8 bb = *(const bf16x8*)(W2p + (size_t)((kc * 4 + wc2 * 2 + ncl) * 64 + lane) * 8);
                acc2[ncl] = __builtin_amdgcn_mfma_f32_16x16x32_bf16(a, bb, acc2[ncl], 0, 0, 0);
            }
        }
        #pragma unroll
        for (int ncl = 0; ncl < 2; ++ncl) {
            const int col2 = wc2 * 32 + ncl * 16 + m;
            const float bias = b2[col2];
            #pragma unroll
            for (int reg = 0; reg < 4; ++reg) {
                const int row2 = mr * 16 + kg * 4 + reg;
                h2s[row2][col2] = fmaxf(acc2[ncl][reg] + bias, 0.f);
            }
        }
    }
    __syncthreads();

    // ---- Layer 3 + output: wave handles rows [8*wave, +8); lane: col3 = lane&31,
    // rsel = lane>>5 picks row sub-group. Shuffle-reduce 32 lanes for the dot.
    {
        const int col3 = lane & 31, rsel = lane >> 5;
        const int rbase = wave * 8 + rsel * 4;
        float acc3[4];
        const float bias3 = b3[col3];
        #pragma unroll
        for (int ri = 0; ri < 4; ++ri) acc3[ri] = bias3;
        #pragma unroll
        for (int k = 0; k < 64; k += 4) {
            float4 w;
            w.x = W3s[(k + 0) * 32 + col3];
            w.y = W3s[(k + 1) * 32 + col3];
            w.z = W3s[(k + 2) * 32 + col3];
            w.w = W3s[(k + 3) * 32 + col3];
            #pragma unroll
            for (int ri = 0; ri < 4; ++ri) {
                const float4 h = *(const float4*)&h2s[rbase + ri][k];
                acc3[ri] = fmaf(h.x, w.x, fmaf(h.y, w.y, fmaf(h.z, w.z, fmaf(h.w, w.w, acc3[ri]))));
            }
        }
        const float wo = Wo[col3], bo0 = bo[0];
        #pragma unroll
        for (int ri = 0; ri < 4; ++ri) {
            float v = fmaxf(acc3[ri], 0.f) * wo;
            v += __shfl_xor(v, 16, 64);
            v += __shfl_xor(v, 8, 64);
            v += __shfl_xor(v, 4, 64);
            v += __shfl_xor(v, 2, 64);
            v += __shfl_xor(v, 1, 64);
            if (col3 == 0) out[row0 + rbase + ri] = v + bo0;
        }
    }
}

// ===========================================================================
// FALLBACK (round-1 f32 path, used only if ws_size is too small)
// ===========================================================================

__global__ __launch_bounds__(64)
void nnue_accum_f32(const int* __restrict__ widx, const int* __restrict__ bidx,
                    const int* __restrict__ wbatch, const int* __restrict__ bbatch,
                    const int* __restrict__ stm,
                    const float* __restrict__ wemb, const float* __restrict__ bemb,
                    float* __restrict__ x, int n_act)
{
    const int b = blockIdx.x, side = blockIdx.y;
    const int*   __restrict__ idx   = side ? bidx   : widx;
    const int*   __restrict__ batch = side ? bbatch : wbatch;
    const float* __restrict__ emb   = side ? bemb   : wemb;
    const int start = lower_bound_i(batch, n_act, b);
    const int end   = lower_bound_i(batch, n_act, b + 1);
    const int c = threadIdx.x << 2;
    float4 s0 = make_float4(0.f, 0.f, 0.f, 0.f);
    float4 s1 = s0, s2 = s0, s3 = s0;
    int r = start;
    for (; r + 4 <= end; r += 4) {
        const float4 v0 = *(const float4*)(emb + (size_t)idx[r + 0] * 256 + c);
        const float4 v1 = *(const float4*)(emb + (size_t)idx[r + 1] * 256 + c);
        const float4 v2 = *(const float4*)(emb + (size_t)idx[r + 2] * 256 + c);
        const float4 v3 = *(const float4*)(emb + (size_t)idx[r + 3] * 256 + c);
        s0.x += v0.x; s0.y += v0.y; s0.z += v0.z; s0.w += v0.w;
        s1.x += v1.x; s1.y += v1.y; s1.z += v1.z; s1.w += v1.w;
        s2.x += v2.x; s2.y += v2.y; s2.z += v2.z; s2.w += v2.w;
        s3.x += v3.x; s3.y += v3.y; s3.z += v3.z; s3.w += v3.w;
    }
    for (; r < end; ++r) {
        const float4 v0 = *(const float4*)(emb + (size_t)idx[r] * 256 + c);
        s0.x += v0.x; s0.y += v0.y; s0.z += v0.z; s0.w += v0.w;
    }
    s0.x += s1.x + s2.x + s3.x; s0.y += s1.y + s2.y + s3.y;
    s0.z += s1.z + s2.z + s3.z; s0.w += s1.w + s2.w + s3.w;
    const int off = (stm[b] == 0) ? (side ? 0 : 256) : (side ? 256 : 0);
    *(float4*)(x + (size_t)b * 512 + off + c) = s0;
}

__global__ __launch_bounds__(256)
void nnue_layer1_f32(const float* __restrict__ x, const float* __restrict__ W1,
                     const float* __restrict__ b1, float* __restrict__ h1, int B)
{
    __shared__ float xs[16][512];
    const int tid = threadIdx.x;
    const int row0 = blockIdx.x * 16;
    #pragma unroll
    for (int i = 0; i < 8; ++i) {
        const int e = (i * 256 + tid) * 4;
        const int rr = e >> 9, cc = e & 511;
        if (row0 + rr < B)
            *(float4*)&xs[rr][cc] = *(const float4*)(x + (size_t)(row0 + rr) * 512 + cc);
    }
    __syncthreads();
    const int wave = tid >> 6, lane = tid & 63;
    const int j2 = lane * 2, wrow = wave * 4;
    float2 acc[4];
    #pragma unroll
    for (int r2 = 0; r2 < 4; ++r2) { acc[r2].x = b1[j2]; acc[r2].y = b1[j2 + 1]; }
    for (int k = 0; k < 512; k += 4) {
        float4 xv[4];
        #pragma unroll
        for (int r2 = 0; r2 < 4; ++r2) xv[r2] = *(const float4*)&xs[wrow + r2][k];
        #pragma unroll
        for (int kk = 0; kk < 4; ++kk) {
            const float2 w = *(const float2*)(W1 + (size_t)(k + kk) * 128 + j2);
            #pragma unroll
            for (int r2 = 0; r2 < 4; ++r2) {
                const float xvv = (&xv[r2].x)[kk];
                acc[r2].x = fmaf(xvv, w.x, acc[r2].x);
                acc[r2].y = fmaf(xvv, w.y, acc[r2].y);
            }
        }
    }
    #pragma unroll
    for (int r2 = 0; r2 < 4; ++r2) {
        const int row = row0 + wrow + r2;
        if (row < B) {
            float2 o;
            o.x = fmaxf(acc[r2].x, 0.f); o.y = fmaxf(acc[r2].y, 0.f);
            *(float2*)(h1 + (size_t)row * 128 + j2) = o;
        }
    }
}

__global__ __launch_bounds__(256)
void nnue_tail_f32(const float* __restrict__ h1,
                   const float* __restrict__ W2, const float* __restrict__ b2,
                   const float* __restrict__ W3, const float* __restrict__ b3,
                   const float* __restrict__ Wo, const float* __restrict__ bo,
                   float* __restrict__ out, int B)
{
    __shared__ float W2s[128 * 64];
    __shared__ float W3s[64 * 32];
    __shared__ float Wos[32];
    __shared__ float h1row[4][128];
    __shared__ float h2row[4][64];
    const int tid = threadIdx.x;
    for (int i = tid; i < 128 * 64; i += 256) W2s[i] = W2[i];
    for (int i = tid; i < 64 * 32; i += 256)  W3s[i] = W3[i];
    if (tid < 32) Wos[tid] = Wo[tid];
    __syncthreads();
    const int wave = tid >> 6, lane = tid & 63;
    const float bias2 = b2[lane];
    const float bias3 = (lane < 32) ? b3[lane] : 0.f;
    const float wo = (lane < 32) ? Wos[lane] : 0.f;
    const float bo0 = bo[0];
    #pragma unroll 1
    for (int it = 0; it < 8; ++it) {
        const int row = blockIdx.x * 32 + wave * 8 + it;
        if (row >= B) break;
        h1row[wave][lane]      = h1[(size_t)row * 128 + lane];
        h1row[wave][lane + 64] = h1[(size_t)row * 128 + 64 + lane];
        float acc = bias2;
        #pragma unroll 8
        for (int k = 0; k < 128; ++k)
            acc = fmaf(h1row[wave][k], W2s[k * 64 + lane], acc);
        acc = fmaxf(acc, 0.f);
        h2row[wave][lane] = acc;
        float acc3 = 0.f;
        if (lane < 32) {
            acc3 = bias3;
            #pragma unroll 8
            for (int k = 0; k < 64; ++k)
                acc3 = fmaf(h2row[wave][k], W3s[k * 32 + lane], acc3);
            acc3 = fmaxf(acc3, 0.f) * wo;
        }
        #pragma unroll
        for (int sft = 32; sft >= 1; sft >>= 1)
            acc3 += __shfl_xor(acc3, sft, 64);
        if (lane == 0) out[row] = acc3 + bo0;
    }
}

// ===========================================================================

extern "C" void kernel_launch(void* const* d_in, const int* in_sizes, int n_in,
                              void* d_out, int out_size, void* d_ws, size_t ws_size,
                              hipStream_t stream)
{
    const int*   widx   = (const int*)d_in[0];
    const int*   bidx   = (const int*)d_in[1];
    const int*   wbatch = (const int*)d_in[2];
    const int*   bbatch = (const int*)d_in[3];
    const int*   stm    = (const int*)d_in[4];
    const float* wemb   = (const float*)d_in[5];
    const float* bemb   = (const float*)d_in[6];
    const float* W1     = (const float*)d_in[7];
    const float* b1     = (const float*)d_in[8];
    const float* W2     = (const float*)d_in[9];
    const float* b2     = (const float*)d_in[10];
    const float* W3     = (const float*)d_in[11];
    const float* b3     = (const float*)d_in[12];
    const float* Wo     = (const float*)d_in[13];
    const float* bo     = (const float*)d_in[14];

    const int n_act = in_sizes[0];
    const int B     = in_sizes[4];
    const size_t embN = (size_t)in_sizes[5];   // 40960*256

    // workspace layout (fast path)
    char* p = (char*)d_ws;
    unsigned short* wemb16 = (unsigned short*)p; p += embN * 2;
    unsigned short* bemb16 = (unsigned short*)p; p += embN * 2;
    unsigned short* x16    = (unsigned short*)p; p += (size_t)B * 512 * 2;
    unsigned short* W1p    = (unsigned short*)p; p += 65536 * 2;
    unsigned short* W2p    = (unsigned short*)p; p += 8192 * 2;
    int*            segs   = (int*)p;            p += (size_t)2 * (B + 1) * 4;
    const size_t needed = (size_t)(p - (char*)d_ws);

    if (ws_size >= needed && (B % 32) == 0) {
        const long long groups = (long long)(embN / 8);
        nnue_prep<<<2048, 256, 0, stream>>>(wemb, bemb, W1, W2, wbatch, bbatch,
                                            wemb16, bemb16, W1p, W2p, segs,
                                            groups, n_act, B);
        dim3 gA(B / 4, 2);
        nnue_accum16<<<gA, 256, 0, stream>>>(widx, bidx, stm, wemb16, bemb16,
                                             segs, x16, B);
        nnue_mlp16<<<B / 32, 256, 0, stream>>>(x16, W1p, b1, W2p, b2,
                                               W3, b3, Wo, bo, (float*)d_out, B);
    } else {
        float* x  = (float*)d_ws;
        float* h1 = x + (size_t)B * 512;
        dim3 gA(B, 2);
        nnue_accum_f32<<<gA, 64, 0, stream>>>(widx, bidx, wbatch, bbatch, stm,
                                              wemb, bemb, x, n_act);
        nnue_layer1_f32<<<(B + 15) / 16, 256, 0, stream>>>(x, W1, b1, h1, B);
        nnue_tail_f32<<<(B + 31) / 32, 256, 0, stream>>>(h1, W2, b2, W3, b3, Wo, bo,
                                                         (float*)d_out, B);
    }
}